// Round 12
// baseline (302.090 us; speedup 1.0000x reference)
//
#include <hip/hip_runtime.h>
#include <hip/hip_bf16.h>

// B=4, T=2048, D=768, H=12, DH=64, causal MHA + QKV/out projections.
// All inputs fp32; internals bf16 (threshold 8*bf16eps permits this).
//
// R12: (1) GEMM prefetch ordering reverted to R10 (R11's prefetch-first made
// compiler alias analysis insert vmcnt before the frag ds_reads — regression).
// (2) attn: V removed from LDS — bv frags are direct per-wave global loads
// (wave-independent data, L1/L2-hot, issued ~700cyc before PV use); LDS
// 51->34 KB -> 4 blocks/CU; masked chunks skip V entirely.
// (3) proj: BK=64 — 12 barriers instead of 24, 16 MFMAs per barrier.

#define BATCH  4
#define SEQ    2048
#define DMODEL 768
#define NH     12
#define DHEAD  64
static constexpr float SCALE_LOG2E = 0.125f * 1.4426950408889634f;

#define N_X  (8192 * 768)
#define N_WQ (2304 * 768)
#define N_WP (768 * 768)

typedef __bf16 v8bf __attribute__((ext_vector_type(8)));
typedef __bf16 v4bf __attribute__((ext_vector_type(4)));
typedef float  v4f  __attribute__((ext_vector_type(4)));

__device__ __forceinline__ v8bf cvt8(const float* __restrict__ p) {
    const float4 a = ((const float4*)p)[0];
    const float4 b = ((const float4*)p)[1];
    v8bf r;
    r[0] = (__bf16)a.x; r[1] = (__bf16)a.y; r[2] = (__bf16)a.z; r[3] = (__bf16)a.w;
    r[4] = (__bf16)b.x; r[5] = (__bf16)b.y; r[6] = (__bf16)b.z; r[7] = (__bf16)b.w;
    return r;
}

__device__ __forceinline__ void async_copy16(__bf16* lds, const __bf16* g) {
    __builtin_amdgcn_global_load_lds(
        (const __attribute__((address_space(1))) void*)g,
        (__attribute__((address_space(3))) void*)lds, 16, 0, 0);
}

// ---------------------------------------------------------------------------
// Kernel 0: fp32 -> bf16 convert of x, Wqkv, Wproj.
// ---------------------------------------------------------------------------
__global__ __launch_bounds__(256) void cvt_kernel(
        const float* __restrict__ x, const float* __restrict__ Wq,
        const float* __restrict__ Wp, __bf16* __restrict__ xb,
        __bf16* __restrict__ Wqb, __bf16* __restrict__ Wpb) {
    const long e = ((long)blockIdx.x * 256 + threadIdx.x) * 8;
    const float* src;
    __bf16* dst;
    if (e < N_X)             { src = x  + e;               dst = xb  + e; }
    else if (e < N_X + N_WQ) { src = Wq + (e - N_X);        dst = Wqb + (e - N_X); }
    else                     { src = Wp + (e - N_X - N_WQ); dst = Wpb + (e - N_X - N_WQ); }
    *(v8bf*)dst = cvt8(src);
}

// ---------------------------------------------------------------------------
// Kernel 1: qkv = xb @ Wqkvb^T (M=8192, N=2304, K=768). R10 proven version.
// ---------------------------------------------------------------------------
__global__ __launch_bounds__(256) void qkv_gemm(
        const __bf16* __restrict__ xb, const __bf16* __restrict__ Wb,
        __bf16* __restrict__ Qb, __bf16* __restrict__ Kb, __bf16* __restrict__ Vtb) {
    __shared__ __bf16 As[2][128 * 32], Bs[2][128 * 32];   // 32 KB
    const int lane = threadIdx.x & 63, wave = threadIdx.x >> 6;
    const int i = blockIdx.x;
    const int mb = ((i & 7) << 3) | ((i >> 3) & 7);       // [0,64)
    const int nb = i >> 6;                                // [0,18)
    const int r16 = lane & 15, quad = lane >> 4;
    const int wm = (wave >> 1) * 64, wn = (wave & 1) * 64;
    const __bf16* Asrc = xb + (size_t)mb * 128 * DMODEL;
    const __bf16* Bsrc = Wb + (size_t)nb * 128 * DMODEL;

    const int srow = wave * 16 + (lane >> 2);
    const int sg   = lane & 3;
    const int g    = sg ^ ((srow >> 1) & 3);
    const size_t soff0 = (size_t)srow * DMODEL + g * 8;
    const size_t soff1 = (size_t)(srow + 64) * DMODEL + g * 8;
    const int ld0 = wave * 512;
    const int ld1 = 2048 + wave * 512;
    const int p_rd = quad ^ ((r16 >> 1) & 3);

    async_copy16(&As[0][ld0], Asrc + soff0);
    async_copy16(&As[0][ld1], Asrc + soff1);
    async_copy16(&Bs[0][ld0], Bsrc + soff0);
    async_copy16(&Bs[0][ld1], Bsrc + soff1);

    v4f acc[4][4] = {};
    for (int c = 0; c < 24; ++c) {
        const int cur = c & 1;
        __syncthreads();
        v8bf a[4], b[4];
#pragma unroll
        for (int ii = 0; ii < 4; ++ii)
            a[ii] = *(const v8bf*)&As[cur][(wm + 16 * ii + r16) * 32 + p_rd * 8];
#pragma unroll
        for (int j = 0; j < 4; ++j)
            b[j] = *(const v8bf*)&Bs[cur][(wn + 16 * j + r16) * 32 + p_rd * 8];
        if (c + 1 < 24) {
            const int nxt = cur ^ 1;
            const size_t k1 = (c + 1) * 32;
            async_copy16(&As[nxt][ld0], Asrc + soff0 + k1);
            async_copy16(&As[nxt][ld1], Asrc + soff1 + k1);
            async_copy16(&Bs[nxt][ld0], Bsrc + soff0 + k1);
            async_copy16(&Bs[nxt][ld1], Bsrc + soff1 + k1);
        }
#pragma unroll
        for (int ii = 0; ii < 4; ++ii)
#pragma unroll
            for (int j = 0; j < 4; ++j)
                acc[ii][j] = __builtin_amdgcn_mfma_f32_16x16x32_bf16(
                    a[ii], b[j], acc[ii][j], 0, 0, 0);
    }

    const int seg = nb / 6;
    const int nl0 = (nb % 6) * 128 + wn;
#pragma unroll
    for (int j = 0; j < 4; ++j) {
        const int n = nl0 + 16 * j + r16;
        const int h = n >> 6, d = n & 63;
#pragma unroll
        for (int ii = 0; ii < 4; ++ii) {
            const int mrow = mb * 128 + wm + 16 * ii + quad * 4;
            const int bidx = mrow >> 11, t0 = mrow & (SEQ - 1);
            const size_t base = ((size_t)(bidx * NH + h)) * SEQ * DHEAD;
            if (seg == 2) {                       // V^T: 4 consecutive t packed
                v4bf pk;
#pragma unroll
                for (int r = 0; r < 4; ++r) pk[r] = (__bf16)acc[ii][j][r];
                *(v4bf*)&Vtb[base + (size_t)d * SEQ + t0] = pk;
            } else if (seg == 0) {
#pragma unroll
                for (int r = 0; r < 4; ++r)
                    Qb[base + (size_t)(t0 + r) * DHEAD + d] =
                        (__bf16)(acc[ii][j][r] * SCALE_LOG2E);
            } else {
#pragma unroll
                for (int r = 0; r < 4; ++r)
                    Kb[base + (size_t)(t0 + r) * DHEAD + d] = (__bf16)acc[ii][j][r];
            }
        }
    }
}

// ---------------------------------------------------------------------------
// Kernel 2: MFMA causal flash attention. R12: V direct-from-global (no LDS),
// K staged in LDS dbuf; LDS 34 KB -> 4 blocks/CU. lgkm-only mid-chunk wait.
// ---------------------------------------------------------------------------
__global__ __launch_bounds__(256, 4) void attn_kernel(
        const __bf16* __restrict__ Qb, const __bf16* __restrict__ Kb,
        const __bf16* __restrict__ Vtb, __bf16* __restrict__ attnb) {
    __shared__ __bf16 Ks[2][2][64 * 32];            // 16 KB
    __shared__ __align__(16) __bf16 Pl[4][32 * 72]; // 18 KB
    const int lane = threadIdx.x & 63;
    const int wave = threadIdx.x >> 6;
    const int bh = blockIdx.x % 48;
    const int qt = 15 - (blockIdx.x / 48);
    const int q0 = qt * 128 + wave * 32;
    const int r16 = lane & 15, quad = lane >> 4;

    const __bf16* Q  = Qb  + (size_t)bh * SEQ * DHEAD;
    const __bf16* K  = Kb  + (size_t)bh * SEQ * DHEAD;
    const __bf16* Vt = Vtb + (size_t)bh * DHEAD * SEQ;

    const int srow = wave * 16 + (lane >> 2);
    const int sg   = lane & 3;
    const int g    = sg ^ ((srow >> 1) & 3);
    const int ldw  = wave * 512;
    const int p_rd = quad ^ ((r16 >> 1) & 3);

    v8bf aq[2][2];
#pragma unroll
    for (int ii = 0; ii < 2; ++ii)
#pragma unroll
        for (int kk = 0; kk < 2; ++kk)
            aq[ii][kk] = *(const v8bf*)(Q + (size_t)(q0 + 16 * ii + r16) * DHEAD
                                          + kk * 32 + quad * 8);

    v8bf vones;
#pragma unroll
    for (int j = 0; j < 8; ++j) vones[j] = (__bf16)1.0f;

    v4f oacc[2][4] = {};
    v4f lacc[2] = {};

    const int nchunks = 2 * (qt + 1);
#pragma unroll
    for (int kk = 0; kk < 2; ++kk)
        async_copy16(&Ks[0][kk][ldw], K + (size_t)srow * DHEAD + kk * 32 + g * 8);

    for (int c = 0; c < nchunks; ++c) {
        const int k0 = c * 64;
        const int cur = c & 1;
        __syncthreads();
        // K frags from LDS (chunk c)
        v8bf bk[4][2];
#pragma unroll
        for (int s = 0; s < 4; ++s)
#pragma unroll
            for (int kk = 0; kk < 2; ++kk)
                bk[s][kk] = *(const v8bf*)&Ks[cur][kk][(16 * s + r16) * 32 + p_rd * 8];
        // prefetch K chunk c+1 (R10 position: after frag reads)
        if (c + 1 < nchunks) {
            const int nxt = cur ^ 1;
            const int k1 = k0 + 64;
#pragma unroll
            for (int kk = 0; kk < 2; ++kk)
                async_copy16(&Ks[nxt][kk][ldw],
                             K + (size_t)(k1 + srow) * DHEAD + kk * 32 + g * 8);
        }
        if (k0 > q0 + 31) continue;              // fully masked for this wave

        // V frags direct from global (wave-independent, L1/L2-hot; first use
        // is ~700 cyc away at PV — latency hidden behind QK + softmax)
        v8bf bv[2][4];
#pragma unroll
        for (int kk = 0; kk < 2; ++kk)
#pragma unroll
            for (int n = 0; n < 4; ++n)
                bv[kk][n] = *(const v8bf*)(Vt + (size_t)(16 * n + r16) * SEQ
                                             + k0 + kk * 32 + quad * 8);

        // ---- QK^T ----
        v4f sc[2][4] = {};
#pragma unroll
        for (int kk = 0; kk < 2; ++kk)
#pragma unroll
            for (int ii = 0; ii < 2; ++ii)
#pragma unroll
                for (int s = 0; s < 4; ++s)
                    sc[ii][s] = __builtin_amdgcn_mfma_f32_16x16x32_bf16(
                        aq[ii][kk], bk[s][kk], sc[ii][s], 0, 0, 0);

        // ---- causal mask (diagonal chunks only) ----
        if (k0 + 63 > q0) {
#pragma unroll
            for (int ii = 0; ii < 2; ++ii)
#pragma unroll
                for (int s = 0; s < 4; ++s)
#pragma unroll
                    for (int r = 0; r < 4; ++r) {
                        const int row = q0 + 16 * ii + quad * 4 + r;
                        const int col = k0 + 16 * s + r16;
                        if (col > row) sc[ii][s][r] = -1e30f;
                    }
        }

        // ---- p = exp2(s)  (unbiased; scale folded into Q) ----
#pragma unroll
        for (int ii = 0; ii < 2; ++ii)
#pragma unroll
            for (int s = 0; s < 4; ++s)
#pragma unroll
                for (int r = 0; r < 4; ++r)
                    sc[ii][s][r] = __builtin_exp2f(sc[ii][s][r]);

        // ---- P: C-layout regs -> per-wave LDS (bf16) ----
#pragma unroll
        for (int ii = 0; ii < 2; ++ii)
#pragma unroll
            for (int s = 0; s < 4; ++s)
#pragma unroll
                for (int r = 0; r < 4; ++r)
                    Pl[wave][(16 * ii + quad * 4 + r) * 72 + 16 * s + r16] =
                        (__bf16)sc[ii][s][r];
        // lgkmcnt(0) only; K prefetch + V loads stay in flight
        __builtin_amdgcn_s_waitcnt(0xC07F);

        v8bf ap[2][2];
#pragma unroll
        for (int ii = 0; ii < 2; ++ii)
#pragma unroll
            for (int kk = 0; kk < 2; ++kk)
                ap[ii][kk] = *(const v8bf*)&Pl[wave][(16 * ii + r16) * 72 + kk * 32 + quad * 8];
#pragma unroll
        for (int kk = 0; kk < 2; ++kk)
#pragma unroll
            for (int ii = 0; ii < 2; ++ii) {
#pragma unroll
                for (int n = 0; n < 4; ++n)
                    oacc[ii][n] = __builtin_amdgcn_mfma_f32_16x16x32_bf16(
                        ap[ii][kk], bv[kk][n], oacc[ii][n], 0, 0, 0);
                lacc[ii] = __builtin_amdgcn_mfma_f32_16x16x32_bf16(
                    ap[ii][kk], vones, lacc[ii], 0, 0, 0);
            }
    }

    const int b = bh / NH, h = bh - b * NH;
#pragma unroll
    for (int ii = 0; ii < 2; ++ii)
#pragma unroll
        for (int r = 0; r < 4; ++r) {
            const float inv = 1.0f / lacc[ii][r];
            const int t = q0 + 16 * ii + quad * 4 + r;
#pragma unroll
            for (int n = 0; n < 4; ++n) {
                const int d = 16 * n + r16;
                attnb[((size_t)(b * SEQ + t)) * DMODEL + h * DHEAD + d] =
                    (__bf16)(oacc[ii][n][r] * inv);
            }
        }
}

// ---------------------------------------------------------------------------
// Kernel 3: out = attnb @ Wprojb^T + bproj. R12: BK=64 (12 barriers,
// 16 MFMAs each), 8-group cancelling swizzle, 48 KB LDS -> 3 blocks/CU.
// ---------------------------------------------------------------------------
__global__ __launch_bounds__(256) void proj_gemm(
        const __bf16* __restrict__ Ab, const __bf16* __restrict__ Wb,
        const float* __restrict__ bias, float* __restrict__ out) {
    __shared__ __bf16 As[2][64 * 64], Bs[2][128 * 64];   // 16 + 32 KB
    const int lane = threadIdx.x & 63, wave = threadIdx.x >> 6;
    const int i = blockIdx.x;
    const int mb = ((i & 7) << 4) | ((i >> 3) & 15);     // [0,128)
    const int nb = i >> 7;                               // [0,6)
    const int r16 = lane & 15, quad = lane >> 4;
    const int wm = (wave >> 1) * 32, wn = (wave & 1) * 64;
    const __bf16* Asrc = Ab + (size_t)mb * 64 * DMODEL;
    const __bf16* Bsrc = Wb + (size_t)nb * 128 * DMODEL;

    const int tid = threadIdx.x;
    // staging: unit u (16B): row = u>>3, logical grp gl = u&7, store src grp
    // gs = gl ^ (row&7). A: 512 units (64x64), B: 1024 units (128x64).
    const int swA = (tid + 0) >> 3;      // placeholder (computed per copy)
    (void)swA;
    const int p8 = r16 & 7;              // read-side row-XOR

    // per-copy helper offsets
    auto stageA = [&](int buf, int c) {
#pragma unroll
        for (int a = 0; a < 2; ++a) {
            const int ub = a * 256 + wave * 64;
            const int u = ub + lane;
            const int row = u >> 3, gl = u & 7;
            const int gs = gl ^ (row & 7);
            async_copy16(&As[buf][ub * 8],
                         Asrc + (size_t)row * DMODEL + c * 64 + gs * 8);
        }
    };
    auto stageB = [&](int buf, int c) {
#pragma unroll
        for (int a = 0; a < 4; ++a) {
            const int ub = a * 256 + wave * 64;
            const int u = ub + lane;
            const int row = u >> 3, gl = u & 7;
            const int gs = gl ^ (row & 7);
            async_copy16(&Bs[buf][ub * 8],
                         Bsrc + (size_t)row * DMODEL + c * 64 + gs * 8);
        }
    };

    stageA(0, 0);
    stageB(0, 0);

    v4f acc[2][4] = {};
    for (int c = 0; c < 12; ++c) {
        const int cur = c & 1;
        __syncthreads();
        v8bf a[2][2], b[4][2];
#pragma unroll
        for (int ii = 0; ii < 2; ++ii) {
            const int row = wm + 16 * ii + r16;
#pragma unroll
            for (int kk = 0; kk < 2; ++kk) {
                const int gp = (4 * kk + quad) ^ (row & 7);
                a[ii][kk] = *(const v8bf*)&As[cur][(row * 8 + gp) * 8];
            }
        }
#pragma unroll
        for (int j = 0; j < 4; ++j) {
            const int row = wn + 16 * j + r16;
#pragma unroll
            for (int kk = 0; kk < 2; ++kk) {
                const int gp = (4 * kk + quad) ^ (row & 7);
                b[j][kk] = *(const v8bf*)&Bs[cur][(row * 8 + gp) * 8];
            }
        }
        if (c + 1 < 12) {
            const int nxt = cur ^ 1;
            stageA(nxt, c + 1);
            stageB(nxt, c + 1);
        }
#pragma unroll
        for (int kk = 0; kk < 2; ++kk)
#pragma unroll
            for (int ii = 0; ii < 2; ++ii)
#pragma unroll
                for (int j = 0; j < 4; ++j)
                    acc[ii][j] = __builtin_amdgcn_mfma_f32_16x16x32_bf16(
                        a[ii][kk], b[j][kk], acc[ii][j], 0, 0, 0);
    }

#pragma unroll
    for (int j = 0; j < 4; ++j) {
        const int n = nb * 128 + wn + 16 * j + r16;
        const float bv = bias[n];
#pragma unroll
        for (int ii = 0; ii < 2; ++ii) {
            const int mrow = mb * 64 + wm + 16 * ii + quad * 4;
#pragma unroll
            for (int r = 0; r < 4; ++r)
                out[(size_t)(mrow + r) * DMODEL + n] = acc[ii][j][r] + bv;
        }
    }
}

// ---------------------------------------------------------------------------
extern "C" void kernel_launch(void* const* d_in, const int* in_sizes, int n_in,
                              void* d_out, int out_size, void* d_ws, size_t ws_size,
                              hipStream_t stream) {
    const float* x     = (const float*)d_in[0];
    const float* Wqkv  = (const float*)d_in[1];
    const float* Wproj = (const float*)d_in[2];
    const float* bproj = (const float*)d_in[3];
    float* out = (float*)d_out;

    char* ws = (char*)d_ws;
    const size_t tsz = (size_t)BATCH * NH * SEQ * DHEAD * sizeof(__bf16); // 12.58 MB
    __bf16* Qb    = (__bf16*)(ws);
    __bf16* Kb    = (__bf16*)(ws + tsz);
    __bf16* Vtb   = (__bf16*)(ws + 2 * tsz);          // [B,H,DH,T]
    __bf16* xb    = (__bf16*)(ws + 3 * tsz);          // aliased with attnb:
    __bf16* attnb = (__bf16*)(ws + 3 * tsz);          // xb dead before attn writes
    __bf16* Wqb   = (__bf16*)(ws + 4 * tsz);
    __bf16* Wpb   = (__bf16*)(ws + 4 * tsz + (size_t)N_WQ * 2);

    cvt_kernel<<<dim3((N_X + N_WQ + N_WP) / (8 * 256)), dim3(256), 0, stream>>>(
        x, Wqkv, Wproj, xb, Wqb, Wpb);
    qkv_gemm<<<dim3(64 * 18), dim3(256), 0, stream>>>(xb, Wqb, Qb, Kb, Vtb);
    attn_kernel<<<dim3(16 * 48), dim3(256), 0, stream>>>(Qb, Kb, Vtb, attnb);
    proj_gemm<<<dim3(128 * 6), dim3(256), 0, stream>>>(attnb, Wpb, bproj, out);
}

// Round 13
// 199.753 us; speedup vs baseline: 1.5123x; 1.5123x over previous
//
#include <hip/hip_runtime.h>
#include <hip/hip_bf16.h>

// B=4, T=2048, D=768, H=12, DH=64, causal MHA + QKV/out projections.
// All inputs fp32; internals bf16 (threshold 8*bf16eps permits this).
//
// R13: recovery. attn reverted EXACTLY to R10 (R12's launch_bounds(256,4)
// forced a 64-VGPR tier while V-in-regs needed ~170 live -> scratch spill,
// WRITE_SIZE 12->122 MB, 66->175 us). proj keeps R12's BK=64 (the one
// improvement: 12 barriers, 16 MFMAs/barrier). qkv/cvt = R10 proven.

#define BATCH  4
#define SEQ    2048
#define DMODEL 768
#define NH     12
#define DHEAD  64
static constexpr float SCALE_LOG2E = 0.125f * 1.4426950408889634f;

#define N_X  (8192 * 768)
#define N_WQ (2304 * 768)
#define N_WP (768 * 768)

typedef __bf16 v8bf __attribute__((ext_vector_type(8)));
typedef __bf16 v4bf __attribute__((ext_vector_type(4)));
typedef float  v4f  __attribute__((ext_vector_type(4)));

__device__ __forceinline__ v8bf cvt8(const float* __restrict__ p) {
    const float4 a = ((const float4*)p)[0];
    const float4 b = ((const float4*)p)[1];
    v8bf r;
    r[0] = (__bf16)a.x; r[1] = (__bf16)a.y; r[2] = (__bf16)a.z; r[3] = (__bf16)a.w;
    r[4] = (__bf16)b.x; r[5] = (__bf16)b.y; r[6] = (__bf16)b.z; r[7] = (__bf16)b.w;
    return r;
}

__device__ __forceinline__ void async_copy16(__bf16* lds, const __bf16* g) {
    __builtin_amdgcn_global_load_lds(
        (const __attribute__((address_space(1))) void*)g,
        (__attribute__((address_space(3))) void*)lds, 16, 0, 0);
}

// ---------------------------------------------------------------------------
// Kernel 0: fp32 -> bf16 convert of x, Wqkv, Wproj.
// ---------------------------------------------------------------------------
__global__ __launch_bounds__(256) void cvt_kernel(
        const float* __restrict__ x, const float* __restrict__ Wq,
        const float* __restrict__ Wp, __bf16* __restrict__ xb,
        __bf16* __restrict__ Wqb, __bf16* __restrict__ Wpb) {
    const long e = ((long)blockIdx.x * 256 + threadIdx.x) * 8;
    const float* src;
    __bf16* dst;
    if (e < N_X)             { src = x  + e;               dst = xb  + e; }
    else if (e < N_X + N_WQ) { src = Wq + (e - N_X);        dst = Wqb + (e - N_X); }
    else                     { src = Wp + (e - N_X - N_WQ); dst = Wpb + (e - N_X - N_WQ); }
    *(v8bf*)dst = cvt8(src);
}

// ---------------------------------------------------------------------------
// Kernel 1: qkv = xb @ Wqkvb^T (M=8192, N=2304, K=768). R10 proven version.
// ---------------------------------------------------------------------------
__global__ __launch_bounds__(256) void qkv_gemm(
        const __bf16* __restrict__ xb, const __bf16* __restrict__ Wb,
        __bf16* __restrict__ Qb, __bf16* __restrict__ Kb, __bf16* __restrict__ Vtb) {
    __shared__ __bf16 As[2][128 * 32], Bs[2][128 * 32];   // 32 KB
    const int lane = threadIdx.x & 63, wave = threadIdx.x >> 6;
    const int i = blockIdx.x;
    const int mb = ((i & 7) << 3) | ((i >> 3) & 7);       // [0,64)
    const int nb = i >> 6;                                // [0,18)
    const int r16 = lane & 15, quad = lane >> 4;
    const int wm = (wave >> 1) * 64, wn = (wave & 1) * 64;
    const __bf16* Asrc = xb + (size_t)mb * 128 * DMODEL;
    const __bf16* Bsrc = Wb + (size_t)nb * 128 * DMODEL;

    const int srow = wave * 16 + (lane >> 2);
    const int sg   = lane & 3;
    const int g    = sg ^ ((srow >> 1) & 3);
    const size_t soff0 = (size_t)srow * DMODEL + g * 8;
    const size_t soff1 = (size_t)(srow + 64) * DMODEL + g * 8;
    const int ld0 = wave * 512;
    const int ld1 = 2048 + wave * 512;
    const int p_rd = quad ^ ((r16 >> 1) & 3);

    async_copy16(&As[0][ld0], Asrc + soff0);
    async_copy16(&As[0][ld1], Asrc + soff1);
    async_copy16(&Bs[0][ld0], Bsrc + soff0);
    async_copy16(&Bs[0][ld1], Bsrc + soff1);

    v4f acc[4][4] = {};
    for (int c = 0; c < 24; ++c) {
        const int cur = c & 1;
        __syncthreads();
        v8bf a[4], b[4];
#pragma unroll
        for (int ii = 0; ii < 4; ++ii)
            a[ii] = *(const v8bf*)&As[cur][(wm + 16 * ii + r16) * 32 + p_rd * 8];
#pragma unroll
        for (int j = 0; j < 4; ++j)
            b[j] = *(const v8bf*)&Bs[cur][(wn + 16 * j + r16) * 32 + p_rd * 8];
        if (c + 1 < 24) {
            const int nxt = cur ^ 1;
            const size_t k1 = (c + 1) * 32;
            async_copy16(&As[nxt][ld0], Asrc + soff0 + k1);
            async_copy16(&As[nxt][ld1], Asrc + soff1 + k1);
            async_copy16(&Bs[nxt][ld0], Bsrc + soff0 + k1);
            async_copy16(&Bs[nxt][ld1], Bsrc + soff1 + k1);
        }
#pragma unroll
        for (int ii = 0; ii < 4; ++ii)
#pragma unroll
            for (int j = 0; j < 4; ++j)
                acc[ii][j] = __builtin_amdgcn_mfma_f32_16x16x32_bf16(
                    a[ii], b[j], acc[ii][j], 0, 0, 0);
    }

    const int seg = nb / 6;
    const int nl0 = (nb % 6) * 128 + wn;
#pragma unroll
    for (int j = 0; j < 4; ++j) {
        const int n = nl0 + 16 * j + r16;
        const int h = n >> 6, d = n & 63;
#pragma unroll
        for (int ii = 0; ii < 4; ++ii) {
            const int mrow = mb * 128 + wm + 16 * ii + quad * 4;
            const int bidx = mrow >> 11, t0 = mrow & (SEQ - 1);
            const size_t base = ((size_t)(bidx * NH + h)) * SEQ * DHEAD;
            if (seg == 2) {                       // V^T: 4 consecutive t packed
                v4bf pk;
#pragma unroll
                for (int r = 0; r < 4; ++r) pk[r] = (__bf16)acc[ii][j][r];
                *(v4bf*)&Vtb[base + (size_t)d * SEQ + t0] = pk;
            } else if (seg == 0) {
#pragma unroll
                for (int r = 0; r < 4; ++r)
                    Qb[base + (size_t)(t0 + r) * DHEAD + d] =
                        (__bf16)(acc[ii][j][r] * SCALE_LOG2E);
            } else {
#pragma unroll
                for (int r = 0; r < 4; ++r)
                    Kb[base + (size_t)(t0 + r) * DHEAD + d] = (__bf16)acc[ii][j][r];
            }
        }
    }
}

// ---------------------------------------------------------------------------
// Kernel 2: MFMA causal flash attention. EXACT R10 version (proven 66 us):
// K+V LDS dbuf, prefetch after frag reads, lgkm-only mid-chunk wait,
// unbiased exp2, launch_bounds(256,3).
// ---------------------------------------------------------------------------
__global__ __launch_bounds__(256, 3) void attn_kernel(
        const __bf16* __restrict__ Qb, const __bf16* __restrict__ Kb,
        const __bf16* __restrict__ Vtb, __bf16* __restrict__ attnb) {
    __shared__ __bf16 Ks[2][2][64 * 32];
    __shared__ __bf16 Vs[2][2][64 * 32];
    __shared__ __align__(16) __bf16 Pl[4][32 * 72];
    const int lane = threadIdx.x & 63;
    const int wave = threadIdx.x >> 6;
    const int bh = blockIdx.x % 48;
    const int qt = 15 - (blockIdx.x / 48);
    const int q0 = qt * 128 + wave * 32;
    const int r16 = lane & 15, quad = lane >> 4;

    const __bf16* Q  = Qb  + (size_t)bh * SEQ * DHEAD;
    const __bf16* K  = Kb  + (size_t)bh * SEQ * DHEAD;
    const __bf16* Vt = Vtb + (size_t)bh * DHEAD * SEQ;

    const int srow = wave * 16 + (lane >> 2);
    const int sg   = lane & 3;
    const int g    = sg ^ ((srow >> 1) & 3);
    const int ldw  = wave * 512;
    const int p_rd = quad ^ ((r16 >> 1) & 3);

    v8bf aq[2][2];
#pragma unroll
    for (int ii = 0; ii < 2; ++ii)
#pragma unroll
        for (int kk = 0; kk < 2; ++kk)
            aq[ii][kk] = *(const v8bf*)(Q + (size_t)(q0 + 16 * ii + r16) * DHEAD
                                          + kk * 32 + quad * 8);

    v8bf vones;
#pragma unroll
    for (int j = 0; j < 8; ++j) vones[j] = (__bf16)1.0f;

    v4f oacc[2][4] = {};
    v4f lacc[2] = {};

    const int nchunks = 2 * (qt + 1);
#pragma unroll
    for (int kk = 0; kk < 2; ++kk) {
        async_copy16(&Ks[0][kk][ldw], K + (size_t)srow * DHEAD + kk * 32 + g * 8);
        async_copy16(&Vs[0][kk][ldw], Vt + (size_t)srow * SEQ + kk * 32 + g * 8);
    }

    for (int c = 0; c < nchunks; ++c) {
        const int k0 = c * 64;
        const int cur = c & 1;
        __syncthreads();
        v8bf bk[4][2], bv[2][4];
#pragma unroll
        for (int s = 0; s < 4; ++s)
#pragma unroll
            for (int kk = 0; kk < 2; ++kk)
                bk[s][kk] = *(const v8bf*)&Ks[cur][kk][(16 * s + r16) * 32 + p_rd * 8];
#pragma unroll
        for (int kk = 0; kk < 2; ++kk)
#pragma unroll
            for (int n = 0; n < 4; ++n)
                bv[kk][n] = *(const v8bf*)&Vs[cur][kk][(16 * n + r16) * 32 + p_rd * 8];
        if (c + 1 < nchunks) {
            const int nxt = cur ^ 1;
            const int k1 = k0 + 64;
#pragma unroll
            for (int kk = 0; kk < 2; ++kk) {
                async_copy16(&Ks[nxt][kk][ldw],
                             K + (size_t)(k1 + srow) * DHEAD + kk * 32 + g * 8);
                async_copy16(&Vs[nxt][kk][ldw],
                             Vt + (size_t)srow * SEQ + k1 + kk * 32 + g * 8);
            }
        }
        if (k0 > q0 + 31) continue;

        v4f sc[2][4] = {};
#pragma unroll
        for (int kk = 0; kk < 2; ++kk)
#pragma unroll
            for (int ii = 0; ii < 2; ++ii)
#pragma unroll
                for (int s = 0; s < 4; ++s)
                    sc[ii][s] = __builtin_amdgcn_mfma_f32_16x16x32_bf16(
                        aq[ii][kk], bk[s][kk], sc[ii][s], 0, 0, 0);

        if (k0 + 63 > q0) {
#pragma unroll
            for (int ii = 0; ii < 2; ++ii)
#pragma unroll
                for (int s = 0; s < 4; ++s)
#pragma unroll
                    for (int r = 0; r < 4; ++r) {
                        const int row = q0 + 16 * ii + quad * 4 + r;
                        const int col = k0 + 16 * s + r16;
                        if (col > row) sc[ii][s][r] = -1e30f;
                    }
        }

#pragma unroll
        for (int ii = 0; ii < 2; ++ii)
#pragma unroll
            for (int s = 0; s < 4; ++s)
#pragma unroll
                for (int r = 0; r < 4; ++r)
                    sc[ii][s][r] = __builtin_exp2f(sc[ii][s][r]);

#pragma unroll
        for (int ii = 0; ii < 2; ++ii)
#pragma unroll
            for (int s = 0; s < 4; ++s)
#pragma unroll
                for (int r = 0; r < 4; ++r)
                    Pl[wave][(16 * ii + quad * 4 + r) * 72 + 16 * s + r16] =
                        (__bf16)sc[ii][s][r];
        // lgkmcnt(0) only; global prefetch stays in flight
        __builtin_amdgcn_s_waitcnt(0xC07F);

        v8bf ap[2][2];
#pragma unroll
        for (int ii = 0; ii < 2; ++ii)
#pragma unroll
            for (int kk = 0; kk < 2; ++kk)
                ap[ii][kk] = *(const v8bf*)&Pl[wave][(16 * ii + r16) * 72 + kk * 32 + quad * 8];
#pragma unroll
        for (int kk = 0; kk < 2; ++kk)
#pragma unroll
            for (int ii = 0; ii < 2; ++ii) {
#pragma unroll
                for (int n = 0; n < 4; ++n)
                    oacc[ii][n] = __builtin_amdgcn_mfma_f32_16x16x32_bf16(
                        ap[ii][kk], bv[kk][n], oacc[ii][n], 0, 0, 0);
                lacc[ii] = __builtin_amdgcn_mfma_f32_16x16x32_bf16(
                    ap[ii][kk], vones, lacc[ii], 0, 0, 0);
            }
    }

    const int b = bh / NH, h = bh - b * NH;
#pragma unroll
    for (int ii = 0; ii < 2; ++ii)
#pragma unroll
        for (int r = 0; r < 4; ++r) {
            const float inv = 1.0f / lacc[ii][r];
            const int t = q0 + 16 * ii + quad * 4 + r;
#pragma unroll
            for (int n = 0; n < 4; ++n) {
                const int d = 16 * n + r16;
                attnb[((size_t)(b * SEQ + t)) * DMODEL + h * DHEAD + d] =
                    (__bf16)(oacc[ii][n][r] * inv);
            }
        }
}

// ---------------------------------------------------------------------------
// Kernel 3: out = attnb @ Wprojb^T + bproj. R12 BK=64 version (kept).
// ---------------------------------------------------------------------------
__global__ __launch_bounds__(256) void proj_gemm(
        const __bf16* __restrict__ Ab, const __bf16* __restrict__ Wb,
        const float* __restrict__ bias, float* __restrict__ out) {
    __shared__ __bf16 As[2][64 * 64], Bs[2][128 * 64];   // 16 + 32 KB
    const int lane = threadIdx.x & 63, wave = threadIdx.x >> 6;
    const int i = blockIdx.x;
    const int mb = ((i & 7) << 4) | ((i >> 3) & 15);     // [0,128)
    const int nb = i >> 7;                               // [0,6)
    const int r16 = lane & 15, quad = lane >> 4;
    const int wm = (wave >> 1) * 32, wn = (wave & 1) * 64;
    const __bf16* Asrc = Ab + (size_t)mb * 64 * DMODEL;
    const __bf16* Bsrc = Wb + (size_t)nb * 128 * DMODEL;

    auto stageA = [&](int buf, int c) {
#pragma unroll
        for (int a = 0; a < 2; ++a) {
            const int ub = a * 256 + wave * 64;
            const int u = ub + lane;
            const int row = u >> 3, gl = u & 7;
            const int gs = gl ^ (row & 7);
            async_copy16(&As[buf][ub * 8],
                         Asrc + (size_t)row * DMODEL + c * 64 + gs * 8);
        }
    };
    auto stageB = [&](int buf, int c) {
#pragma unroll
        for (int a = 0; a < 4; ++a) {
            const int ub = a * 256 + wave * 64;
            const int u = ub + lane;
            const int row = u >> 3, gl = u & 7;
            const int gs = gl ^ (row & 7);
            async_copy16(&Bs[buf][ub * 8],
                         Bsrc + (size_t)row * DMODEL + c * 64 + gs * 8);
        }
    };

    stageA(0, 0);
    stageB(0, 0);

    v4f acc[2][4] = {};
    for (int c = 0; c < 12; ++c) {
        const int cur = c & 1;
        __syncthreads();
        v8bf a[2][2], b[4][2];
#pragma unroll
        for (int ii = 0; ii < 2; ++ii) {
            const int row = wm + 16 * ii + r16;
#pragma unroll
            for (int kk = 0; kk < 2; ++kk) {
                const int gp = (4 * kk + quad) ^ (row & 7);
                a[ii][kk] = *(const v8bf*)&As[cur][(row * 8 + gp) * 8];
            }
        }
#pragma unroll
        for (int j = 0; j < 4; ++j) {
            const int row = wn + 16 * j + r16;
#pragma unroll
            for (int kk = 0; kk < 2; ++kk) {
                const int gp = (4 * kk + quad) ^ (row & 7);
                b[j][kk] = *(const v8bf*)&Bs[cur][(row * 8 + gp) * 8];
            }
        }
        if (c + 1 < 12) {
            const int nxt = cur ^ 1;
            stageA(nxt, c + 1);
            stageB(nxt, c + 1);
        }
#pragma unroll
        for (int kk = 0; kk < 2; ++kk)
#pragma unroll
            for (int ii = 0; ii < 2; ++ii)
#pragma unroll
                for (int j = 0; j < 4; ++j)
                    acc[ii][j] = __builtin_amdgcn_mfma_f32_16x16x32_bf16(
                        a[ii][kk], b[j][kk], acc[ii][j], 0, 0, 0);
    }

#pragma unroll
    for (int j = 0; j < 4; ++j) {
        const int n = nb * 128 + wn + 16 * j + r16;
        const float bv = bias[n];
#pragma unroll
        for (int ii = 0; ii < 2; ++ii) {
            const int mrow = mb * 64 + wm + 16 * ii + quad * 4;
#pragma unroll
            for (int r = 0; r < 4; ++r)
                out[(size_t)(mrow + r) * DMODEL + n] = acc[ii][j][r] + bv;
        }
    }
}

// ---------------------------------------------------------------------------
extern "C" void kernel_launch(void* const* d_in, const int* in_sizes, int n_in,
                              void* d_out, int out_size, void* d_ws, size_t ws_size,
                              hipStream_t stream) {
    const float* x     = (const float*)d_in[0];
    const float* Wqkv  = (const float*)d_in[1];
    const float* Wproj = (const float*)d_in[2];
    const float* bproj = (const float*)d_in[3];
    float* out = (float*)d_out;

    char* ws = (char*)d_ws;
    const size_t tsz = (size_t)BATCH * NH * SEQ * DHEAD * sizeof(__bf16); // 12.58 MB
    __bf16* Qb    = (__bf16*)(ws);
    __bf16* Kb    = (__bf16*)(ws + tsz);
    __bf16* Vtb   = (__bf16*)(ws + 2 * tsz);          // [B,H,DH,T]
    __bf16* xb    = (__bf16*)(ws + 3 * tsz);          // aliased with attnb:
    __bf16* attnb = (__bf16*)(ws + 3 * tsz);          // xb dead before attn writes
    __bf16* Wqb   = (__bf16*)(ws + 4 * tsz);
    __bf16* Wpb   = (__bf16*)(ws + 4 * tsz + (size_t)N_WQ * 2);

    cvt_kernel<<<dim3((N_X + N_WQ + N_WP) / (8 * 256)), dim3(256), 0, stream>>>(
        x, Wqkv, Wproj, xb, Wqb, Wpb);
    qkv_gemm<<<dim3(64 * 18), dim3(256), 0, stream>>>(xb, Wqb, Qb, Kb, Vtb);
    attn_kernel<<<dim3(16 * 48), dim3(256), 0, stream>>>(Qb, Kb, Vtb, attnb);
    proj_gemm<<<dim3(128 * 6), dim3(256), 0, stream>>>(attnb, Wpb, bproj, out);
}